// Round 11
// baseline (141.709 us; speedup 1.0000x reference)
//
#include <hip/hip_runtime.h>
#include <math.h>

// SupervisedContrastiveLoss (R17): half the steps — 64-col steps on the R11 base.
//   row_loss_i = log(S_i) - (h_i . csum[lbl_i] - ||h_i||^2) * invT / pos_cnt_i
//   S_i = sum_{lbl_j != lbl_i} exp(s_ij/T)
// Nine rounds: per-step cost 4.7-6.4us, content-independent (R7 64-col == R8
// 32-col == 5.9us/step at same steps/block); occupancy/atomics/volume/barriers/
// LDS/write-FIFO all falsified. Best structure: R11 (LDS-staged, 4-wave,
// per-step atomics) at 4.7us/step. This round: SAME structure, 64-col steps ->
// steps/block 8.25 -> 4.125 (NSTEPS 2112, H=256 strips). Register audit:
// a[4][8]=128 (AGPR per R11's VGPR_Count=64 evidence), acc[4][4]=64, b live 4,
// rowS 16 -> ~240 combined, fits 2 waves/SIMD (256 budget), no spill.
// LDS: 2 x 32KB dbuf = 64KB -> 2 blocks/CU.
// Predict gemm ~21-26us if per-step-fixed; ~39 kills the theory (-> per-work).

#define NROWS 8192
#define NDIM  256
#define TCOLS 64
#define NSTEPS_TOTAL 2112         // sum over strips by<32 of (128 - 4*by)
#define GEMM_BLOCKS 512           // 2 blocks/CU; 2112/512 = 4.125 steps/block
#define INVT 14.285714285714286f  // 1/0.07
#define SC_LOG2E (14.285714285714286f * 1.4426950408889634f)  // invT * log2(e)
#define MASK_BIAS -30000.0f       // exp2 bias for same-label pairs -> exp == 0

typedef __attribute__((ext_vector_type(8))) short short8;
typedef __attribute__((ext_vector_type(4))) float f32x4;

__device__ __forceinline__ unsigned short f2bf(float f) {
    unsigned int u = __float_as_uint(f);
    u = u + 0x7fffu + ((u >> 16) & 1u);     // RNE
    return (unsigned short)(u >> 16);
}
__device__ __forceinline__ float bf2f(unsigned short s) {
    return __uint_as_float(((unsigned int)s) << 16);
}

#define GLOAD_LDS16(gp, lp) \
    __builtin_amdgcn_global_load_lds((const __attribute__((address_space(1))) void*)(gp), \
                                     (__attribute__((address_space(3))) void*)(lp), 16, 0, 0)

// ================= prep: normalize -> hA bf16; selfsim; neg=0; csum/cnt (16-rep); lblbits
__global__ __launch_bounds__(256) void prep_kernel(const float* __restrict__ x,
                                                   const int* __restrict__ labels,
                                                   unsigned short* __restrict__ hA,
                                                   float* __restrict__ selfsim,
                                                   float* __restrict__ neg,
                                                   float* __restrict__ csum,
                                                   float* __restrict__ cnt,
                                                   int* __restrict__ ticket,
                                                   unsigned* __restrict__ lblbits) {
    __shared__ float sdata[4][2][256];
    __shared__ float cw[4];
    const int tid = threadIdx.x, blk = blockIdx.x;
    const int w = tid >> 6, lane = tid & 63;
    const int row0 = blk * 32;

    float a0[4] = {0.f, 0.f, 0.f, 0.f}, a1[4] = {0.f, 0.f, 0.f, 0.f};
    int c1 = 0;
    for (int i = 0; i < 8; ++i) {
        int row = row0 + w * 8 + i;
        float4 v = *(const float4*)(x + (size_t)row * NDIM + lane * 4);
        float ss = v.x * v.x + v.y * v.y + v.z * v.z + v.w * v.w;
#pragma unroll
        for (int o = 32; o >= 1; o >>= 1) ss += __shfl_xor(ss, o, 64);
        float inv = 1.0f / fmaxf(sqrtf(ss), 1e-12f);
        ushort4 b;
        b.x = f2bf(v.x * inv); b.y = f2bf(v.y * inv);
        b.z = f2bf(v.z * inv); b.w = f2bf(v.w * inv);
        float f0 = bf2f(b.x), f1 = bf2f(b.y), f2 = bf2f(b.z), f3 = bf2f(b.w);
        float s2 = f0 * f0 + f1 * f1 + f2 * f2 + f3 * f3;
#pragma unroll
        for (int o = 32; o >= 1; o >>= 1) s2 += __shfl_xor(s2, o, 64);
        *(ushort4*)(hA + (size_t)row * NDIM + lane * 4) = b;
        if (lane == 0) { selfsim[row] = s2; neg[row] = 0.f; }
        int l = labels[row] & 1;
        c1 += l;
        if (l) { a1[0] += f0; a1[1] += f1; a1[2] += f2; a1[3] += f3; }
        else   { a0[0] += f0; a0[1] += f1; a0[2] += f2; a0[3] += f3; }
    }
    // bit-packed labels for this block's 32 rows
    if (w == 0) {
        unsigned long long bm = __ballot((labels[row0 + (lane & 31)] & 1) != 0);
        if (lane == 0) lblbits[blk] = (unsigned)bm;   // low 32 bits = rows row0..row0+31
    }
#pragma unroll
    for (int k = 0; k < 4; ++k) {
        sdata[w][0][lane * 4 + k] = a0[k];
        sdata[w][1][lane * 4 + k] = a1[k];
    }
    if (lane == 0) cw[w] = (float)c1;
    __syncthreads();
    float s0 = sdata[0][0][tid] + sdata[1][0][tid] + sdata[2][0][tid] + sdata[3][0][tid];
    float s1 = sdata[0][1][tid] + sdata[1][1][tid] + sdata[2][1][tid] + sdata[3][1][tid];
    const int rep = blk & 15;
    atomicAdd(&csum[rep * 512 + tid], s0);
    atomicAdd(&csum[rep * 512 + 256 + tid], s1);
    if (tid == 0) {
        float c = cw[0] + cw[1] + cw[2] + cw[3];
        atomicAdd(&cnt[rep * 2 + 1], c);
        atomicAdd(&cnt[rep * 2 + 0], 32.0f - c);
        if (blk == 0) ticket[0] = 0;
    }
}

// stage one 64-col x K=256 B-tile (32 KB) into LDS buffer `buf`; 8 insts/wave.
// LDS: col-major 512B/col; stored slot sc holds global k-chunk sc ^ (col&7).
__device__ __forceinline__ void stage_b(const unsigned short* __restrict__ hA,
                                        unsigned char* smem, int buf,
                                        int col_g0, int w, int lane) {
#pragma unroll
    for (int t = 0; t < 8; ++t) {
        int c0 = w * 16 + t * 2;                    // wave-uniform local col pair
        int colLocal = c0 + (lane >> 5);
        int g = (lane & 31) ^ (colLocal & 7);       // global k-chunk for stored slot
        const unsigned short* gp = hA + (size_t)(col_g0 + colLocal) * NDIM + g * 8;
        GLOAD_LDS16(gp, smem + buf * 32768 + c0 * 512);
    }
}

// ================= triangle GEMM, 256-row strips, 64-col steps
// Strip by (256 rows) covers cols [256by, 8192) in 64-col steps; t<4 is the
// diagonal region -> rowS only; t>=4 -> rowS + colS (per-step atomics).
// Wave w owns rows [256by+64w, +64) x all 64 cols: a[4][8], acc[4][4].
__global__ __launch_bounds__(256, 2) void gemm_kernel(const unsigned short* __restrict__ hA,
                                                      const unsigned* __restrict__ lblbits,
                                                      float* __restrict__ neg) {
    __shared__ __align__(16) unsigned char smem[65536];    // 2 x 32 KB B-tiles
    const int tid = threadIdx.x;
    // XCD-aware swizzle (bijective, 512 % 8 == 0)
    const int blk = ((int)(blockIdx.x & 7)) * (GEMM_BLOCKS / 8) + ((int)blockIdx.x >> 3);
    const int w = tid >> 6, lane = tid & 63;
    const int quad = lane >> 4, l15 = lane & 15;

    const int s0 = (blk * NSTEPS_TOTAL) / GEMM_BLOCKS;
    const int s1 = ((blk + 1) * NSTEPS_TOTAL) / GEMM_BLOCKS;

    // locate starting strip: cum(by) = by*(130-2*by) steps before strip by
    int by = 0;
    while (by < 31 && (by + 1) * (130 - 2 * (by + 1)) <= s0) ++by;
    int t = s0 - by * (130 - 2 * by);

    // ---- A fragments + row-label mask for current strip (64 rows x K=256 per wave)
    short8 a[4][8];
    unsigned rl;   // 16 bits: label of acc row (mt,quad,r) at bit mt*4+r
    {
        int rw0 = by * 256 + w * 64;
#pragma unroll
        for (int mt = 0; mt < 4; ++mt)
#pragma unroll
            for (int ki = 0; ki < 8; ++ki)
                a[mt][ki] = *(const short8*)(hA +
                    (size_t)(rw0 + mt * 16 + l15) * NDIM + ki * 32 + quad * 8);
        unsigned rb0 = lblbits[rw0 >> 5], rb1 = lblbits[(rw0 >> 5) + 1];
        rl = 0;
#pragma unroll
        for (int mt = 0; mt < 4; ++mt)
#pragma unroll
            for (int r = 0; r < 4; ++r) {
                unsigned rb = (mt < 2) ? rb0 : rb1;
                rl |= ((rb >> ((mt & 1) * 16 + quad * 4 + r)) & 1u) << (mt * 4 + r);
            }
    }

    float rowS[4][4];
#pragma unroll
    for (int mt = 0; mt < 4; ++mt)
#pragma unroll
        for (int r = 0; r < 4; ++r) rowS[mt][r] = 0.f;

    stage_b(hA, smem, 0, by * 256 + t * TCOLS, w, lane);
    __syncthreads();   // buf0 staged

    for (int s = s0; s < s1; ++s) {
        const int buf = (s - s0) & 1;
        const int nst = 128 - 4 * by;
        const bool strip_end = (t == nst - 1);
        const int byn = strip_end ? by + 1 : by;
        const int tn  = strip_end ? 0 : t + 1;
        if (s + 1 < s1) stage_b(hA, smem, buf ^ 1, byn * 256 + tn * TCOLS, w, lane);

        const int colbase = by * 256 + t * TCOLS;
        const unsigned cw0 = lblbits[colbase >> 5];        // cols 0-31 of tile
        const unsigned cw1 = lblbits[(colbase >> 5) + 1];  // cols 32-63
        const unsigned short* Bb = (const unsigned short*)smem + buf * 16384;

        // ---- 64-col compute: 4 col-groups of 16, acc[mt][cg]
        f32x4 acc[4][4];
#pragma unroll
        for (int mt = 0; mt < 4; ++mt)
#pragma unroll
            for (int cg = 0; cg < 4; ++cg)
                acc[mt][cg] = (f32x4){0.f, 0.f, 0.f, 0.f};
#pragma unroll
        for (int ki = 0; ki < 8; ++ki) {
            int sc = (ki * 4 + quad) ^ (l15 & 7);          // (cg*16+l15)&7 == l15&7
#pragma unroll
            for (int cg = 0; cg < 4; ++cg) {
                short8 b = *(const short8*)(Bb + (cg * 16 + l15) * 256 + sc * 8);
#pragma unroll
                for (int mt = 0; mt < 4; ++mt)
                    acc[mt][cg] = __builtin_amdgcn_mfma_f32_16x16x32_bf16(a[mt][ki], b, acc[mt][cg], 0, 0, 0);
            }
        }
        const bool offdiag = (t >= 4);
#pragma unroll
        for (int cg = 0; cg < 4; ++cg) {
            const unsigned cwd = (cg < 2) ? cw0 : cw1;
            const unsigned cbit = (cwd >> ((cg & 1) * 16 + l15)) & 1u;
            const unsigned diff = rl ^ (cbit ? 0xFFFFu : 0u);
            float colS = 0.f;
#pragma unroll
            for (int mt = 0; mt < 4; ++mt)
#pragma unroll
                for (int r = 0; r < 4; ++r) {
                    float bias = ((diff >> (mt * 4 + r)) & 1u) ? 0.f : MASK_BIAS;
                    float e = exp2f(fmaf(acc[mt][cg][r], SC_LOG2E, bias));
                    rowS[mt][r] += e;
                    colS += e;
                }
            if (offdiag) {   // credit S_col (pair's other side)
                colS += __shfl_xor(colS, 16, 64);
                colS += __shfl_xor(colS, 32, 64);
                if (quad == 0) atomicAdd(&neg[colbase + cg * 16 + l15], colS);
            }
        }
        if (strip_end || s == s1 - 1) {
            // flush rowS for current strip
#pragma unroll
            for (int o = 1; o < 16; o <<= 1)
#pragma unroll
                for (int mt = 0; mt < 4; ++mt)
#pragma unroll
                    for (int r = 0; r < 4; ++r)
                        rowS[mt][r] += __shfl_xor(rowS[mt][r], o, 64);
            if (l15 == 0) {
                int rw0 = by * 256 + w * 64;
#pragma unroll
                for (int mt = 0; mt < 4; ++mt)
#pragma unroll
                    for (int r = 0; r < 4; ++r)
                        atomicAdd(&neg[rw0 + mt * 16 + quad * 4 + r], rowS[mt][r]);
            }
            if (s + 1 < s1) {   // load A for next strip, reset accumulators
                int rw0n = byn * 256 + w * 64;
#pragma unroll
                for (int mt = 0; mt < 4; ++mt)
#pragma unroll
                    for (int ki = 0; ki < 8; ++ki)
                        a[mt][ki] = *(const short8*)(hA +
                            (size_t)(rw0n + mt * 16 + l15) * NDIM + ki * 32 + quad * 8);
                unsigned rb0 = lblbits[rw0n >> 5], rb1 = lblbits[(rw0n >> 5) + 1];
                rl = 0;
#pragma unroll
                for (int mt = 0; mt < 4; ++mt)
#pragma unroll
                    for (int r = 0; r < 4; ++r) {
                        unsigned rb = (mt < 2) ? rb0 : rb1;
                        rl |= ((rb >> ((mt & 1) * 16 + quad * 4 + r)) & 1u) << (mt * 4 + r);
                    }
#pragma unroll
                for (int mt = 0; mt < 4; ++mt)
#pragma unroll
                    for (int r = 0; r < 4; ++r) rowS[mt][r] = 0.f;
            }
        }
        by = byn; t = tn;
        __syncthreads();   // waves done reading buf; prefetch drained
    }
}

// ================= rowloss + ticketed finalize (last block writes out)
__global__ __launch_bounds__(256) void rowloss_kernel(const unsigned short* __restrict__ hA,
                                                      const int* __restrict__ labels,
                                                      const float* __restrict__ neg,
                                                      const float* __restrict__ selfsim,
                                                      const float* __restrict__ csum,
                                                      const float* __restrict__ cnt,
                                                      float* __restrict__ pbuf,
                                                      int* __restrict__ ticket,
                                                      float* __restrict__ out) {
    __shared__ float csumS[2][256];
    __shared__ float red[8];
    __shared__ int lastFlag;
    const int tid = threadIdx.x, blk = blockIdx.x;
    const int w = tid >> 6, lane = tid & 63;

    float t0 = 0.f, t1 = 0.f;
#pragma unroll
    for (int r = 0; r < 16; ++r) {
        t0 += csum[r * 512 + tid];
        t1 += csum[r * 512 + 256 + tid];
    }
    csumS[0][tid] = t0;
    csumS[1][tid] = t1;
    __syncthreads();
    float c0v = 0.f, c1v = 0.f;
#pragma unroll
    for (int r = 0; r < 16; ++r) { c0v += cnt[r * 2]; c1v += cnt[r * 2 + 1]; }

    const int row0 = blk * 32;
    float wsum = 0.f, wcnt = 0.f;
    for (int i = 0; i < 8; ++i) {
        int row = row0 + w * 8 + i;
        int l = labels[row] & 1;
        ushort4 hv = *(const ushort4*)(hA + (size_t)row * NDIM + lane * 4);
        const float* cv = &csumS[l][lane * 4];
        float dot = bf2f(hv.x) * cv[0] + bf2f(hv.y) * cv[1] +
                    bf2f(hv.z) * cv[2] + bf2f(hv.w) * cv[3];
#pragma unroll
        for (int o = 32; o >= 1; o >>= 1) dot += __shfl_xor(dot, o, 64);
        if (lane == 0) {
            float pc = (l ? c1v : c0v) - 1.0f;
            float S = neg[row];
            if (pc > 0.5f) {
                wcnt += 1.f;
                if (S > 0.f)
                    wsum += logf(S) - (dot - selfsim[row]) * INVT / pc;
            }
        }
    }
    if (lane == 0) { red[w] = wsum; red[4 + w] = wcnt; }
    __syncthreads();
    if (tid == 0) {
        atomicExch(&pbuf[blk],       red[0] + red[1] + red[2] + red[3]);
        atomicExch(&pbuf[256 + blk], red[4] + red[5] + red[6] + red[7]);
        __threadfence();
        int old = atomicAdd(ticket, 1);
        lastFlag = (old == 255) ? 1 : 0;
    }
    __syncthreads();
    if (lastFlag && tid < 64) {
        __threadfence();
        float v = 0.f, c = 0.f;
#pragma unroll
        for (int k = 0; k < 4; ++k) {
            v += atomicAdd(&pbuf[k * 64 + tid], 0.0f);        // device-scope reads
            c += atomicAdd(&pbuf[256 + k * 64 + tid], 0.0f);
        }
#pragma unroll
        for (int o = 32; o >= 1; o >>= 1) {
            v += __shfl_xor(v, o, 64);
            c += __shfl_xor(c, o, 64);
        }
        if (tid == 0) out[0] = (c > 0.f) ? v / c : 0.f;
    }
}

extern "C" void kernel_launch(void* const* d_in, const int* in_sizes, int n_in,
                              void* d_out, int out_size, void* d_ws, size_t ws_size,
                              hipStream_t stream) {
    const float* x = (const float*)d_in[0];
    const int* labels = (const int*)d_in[1];

    unsigned short* hA = (unsigned short*)d_ws;              // N*D bf16 = 4 MB
    float* wsf       = (float*)d_ws;
    float* selfsim   = wsf + (size_t)NROWS * NDIM / 2;       // 8192
    float* neg       = selfsim + NROWS;                      // 8192
    float* csum      = neg + NROWS;                          // 16*512 = 8192
    float* cnt       = csum + 16 * 512;                      // 32
    float* pbuf      = cnt + 32;                             // 512
    int*   ticket    = (int*)(pbuf + 512);                   // 1
    unsigned* lblbits = (unsigned*)(ticket + 1);             // 256

    hipMemsetAsync(csum, 0, (16 * 512 + 32) * sizeof(float), stream);   // csum + cnt
    prep_kernel<<<256, 256, 0, stream>>>(x, labels, hA, selfsim, neg, csum, cnt, ticket, lblbits);
    gemm_kernel<<<GEMM_BLOCKS, 256, 0, stream>>>(hA, lblbits, neg);
    rowloss_kernel<<<256, 256, 0, stream>>>(hA, labels, neg, selfsim, csum, cnt,
                                            pbuf, ticket, (float*)d_out);
}

// Round 12
// 120.231 us; speedup vs baseline: 1.1786x; 1.1786x over previous
//
#include <hip/hip_runtime.h>
#include <math.h>

// SupervisedContrastiveLoss (R18): R11b + counted vmcnt (guide T4), raw barriers.
//   row_loss_i = log(S_i) - (h_i . csum[lbl_i] - ||h_i||^2) * invT / pos_cnt_i
//   S_i = sum_{lbl_j != lbl_i} exp(s_ij/T)
// R17 lesson: per-wave tile is register-capped at 64x32 (64x64 acc spills ->
// 15.4us/step); fatter steps closed. Base = R11b (best clean: gemm ~39us,
// total 120.5): H=256 strips, 32-col steps, 4 waves, 512 blocks, a[4][8].
// This round's single change: replace per-step __syncthreads() (which emits
// s_waitcnt vmcnt(0) — drains ALL in-flight staging, m233's 72% overhead) with
//   stage(next); s_waitcnt vmcnt(8); s_barrier; compute; s_barrier;
// vmcnt is per-wave in-order: vmcnt(8) after issuing this step's 8 loads
// guarantees prior step's loads + older atomics drained while the fresh 8 stay
// in flight across both barriers (m218: counted-vs-drain0 = +38-73%).
// Race-safety: barrier AFTER each wave's own vmcnt => all waves' loads landed
// before any ds_read; trailing barrier protects buf from next overwrite.

#define NROWS 8192
#define NDIM  256
#define NSTEPS_TOTAL 4224         // sum over strips by<32 of (256 - 8*by)
#define GEMM_BLOCKS 512           // 2 blocks/CU; 8.25 steps/block
#define INVT 14.285714285714286f  // 1/0.07
#define SC_LOG2E (14.285714285714286f * 1.4426950408889634f)  // invT * log2(e)
#define MASK_BIAS -30000.0f       // exp2 bias for same-label pairs -> exp == 0

typedef __attribute__((ext_vector_type(8))) short short8;
typedef __attribute__((ext_vector_type(4))) float f32x4;

__device__ __forceinline__ unsigned short f2bf(float f) {
    unsigned int u = __float_as_uint(f);
    u = u + 0x7fffu + ((u >> 16) & 1u);     // RNE
    return (unsigned short)(u >> 16);
}
__device__ __forceinline__ float bf2f(unsigned short s) {
    return __uint_as_float(((unsigned int)s) << 16);
}

#define GLOAD_LDS16(gp, lp) \
    __builtin_amdgcn_global_load_lds((const __attribute__((address_space(1))) void*)(gp), \
                                     (__attribute__((address_space(3))) void*)(lp), 16, 0, 0)

// ================= prep: normalize -> hA bf16; selfsim; neg=0; csum/cnt (16-rep); lblbits
__global__ __launch_bounds__(256) void prep_kernel(const float* __restrict__ x,
                                                   const int* __restrict__ labels,
                                                   unsigned short* __restrict__ hA,
                                                   float* __restrict__ selfsim,
                                                   float* __restrict__ neg,
                                                   float* __restrict__ csum,
                                                   float* __restrict__ cnt,
                                                   int* __restrict__ ticket,
                                                   unsigned* __restrict__ lblbits) {
    __shared__ float sdata[4][2][256];
    __shared__ float cw[4];
    const int tid = threadIdx.x, blk = blockIdx.x;
    const int w = tid >> 6, lane = tid & 63;
    const int row0 = blk * 32;

    float a0[4] = {0.f, 0.f, 0.f, 0.f}, a1[4] = {0.f, 0.f, 0.f, 0.f};
    int c1 = 0;
    for (int i = 0; i < 8; ++i) {
        int row = row0 + w * 8 + i;
        float4 v = *(const float4*)(x + (size_t)row * NDIM + lane * 4);
        float ss = v.x * v.x + v.y * v.y + v.z * v.z + v.w * v.w;
#pragma unroll
        for (int o = 32; o >= 1; o >>= 1) ss += __shfl_xor(ss, o, 64);
        float inv = 1.0f / fmaxf(sqrtf(ss), 1e-12f);
        ushort4 b;
        b.x = f2bf(v.x * inv); b.y = f2bf(v.y * inv);
        b.z = f2bf(v.z * inv); b.w = f2bf(v.w * inv);
        float f0 = bf2f(b.x), f1 = bf2f(b.y), f2 = bf2f(b.z), f3 = bf2f(b.w);
        float s2 = f0 * f0 + f1 * f1 + f2 * f2 + f3 * f3;
#pragma unroll
        for (int o = 32; o >= 1; o >>= 1) s2 += __shfl_xor(s2, o, 64);
        *(ushort4*)(hA + (size_t)row * NDIM + lane * 4) = b;
        if (lane == 0) { selfsim[row] = s2; neg[row] = 0.f; }
        int l = labels[row] & 1;
        c1 += l;
        if (l) { a1[0] += f0; a1[1] += f1; a1[2] += f2; a1[3] += f3; }
        else   { a0[0] += f0; a0[1] += f1; a0[2] += f2; a0[3] += f3; }
    }
    // bit-packed labels for this block's 32 rows
    if (w == 0) {
        unsigned long long bm = __ballot((labels[row0 + (lane & 31)] & 1) != 0);
        if (lane == 0) lblbits[blk] = (unsigned)bm;   // low 32 bits = rows row0..row0+31
    }
#pragma unroll
    for (int k = 0; k < 4; ++k) {
        sdata[w][0][lane * 4 + k] = a0[k];
        sdata[w][1][lane * 4 + k] = a1[k];
    }
    if (lane == 0) cw[w] = (float)c1;
    __syncthreads();
    float s0 = sdata[0][0][tid] + sdata[1][0][tid] + sdata[2][0][tid] + sdata[3][0][tid];
    float s1 = sdata[0][1][tid] + sdata[1][1][tid] + sdata[2][1][tid] + sdata[3][1][tid];
    const int rep = blk & 15;
    atomicAdd(&csum[rep * 512 + tid], s0);
    atomicAdd(&csum[rep * 512 + 256 + tid], s1);
    if (tid == 0) {
        float c = cw[0] + cw[1] + cw[2] + cw[3];
        atomicAdd(&cnt[rep * 2 + 1], c);
        atomicAdd(&cnt[rep * 2 + 0], 32.0f - c);
        if (blk == 0) ticket[0] = 0;
    }
}

// stage one 32-col x K=256 B-tile (16 KB) into LDS buffer `buf`; 4 insts/wave.
// LDS: col-major 512B/col; stored slot sc holds global k-chunk sc ^ (col&7).
__device__ __forceinline__ void stage_b(const unsigned short* __restrict__ hA,
                                        unsigned char* smem, int buf,
                                        int col_g0, int w, int lane) {
#pragma unroll
    for (int t = 0; t < 4; ++t) {
        int c0 = w * 8 + t * 2;                     // wave-uniform local col pair
        int colLocal = c0 + (lane >> 5);
        int g = (lane & 31) ^ (colLocal & 7);       // global k-chunk for stored slot
        const unsigned short* gp = hA + (size_t)(col_g0 + colLocal) * NDIM + g * 8;
        GLOAD_LDS16(gp, smem + buf * 16384 + c0 * 512);
    }
}

// ================= triangle GEMM, 256-row strips, 32-col steps, counted vmcnt
// Strip by (256 rows) covers cols [256by, 8192) in 32-col steps; t<8 is the
// diagonal region -> rowS only; t>=8 -> rowS + colS (per-step atomics).
// Wave w owns rows [256by+64w, +64): a[4][8]; 8.25 steps/block.
__global__ __launch_bounds__(256, 2) void gemm_kernel(const unsigned short* __restrict__ hA,
                                                      const unsigned* __restrict__ lblbits,
                                                      float* __restrict__ neg) {
    __shared__ __align__(16) unsigned char smem[32768];    // 2 x 16 KB B-tiles
    const int tid = threadIdx.x;
    // XCD-aware swizzle (bijective, 512 % 8 == 0)
    const int blk = ((int)(blockIdx.x & 7)) * (GEMM_BLOCKS / 8) + ((int)blockIdx.x >> 3);
    const int w = tid >> 6, lane = tid & 63;
    const int quad = lane >> 4, l15 = lane & 15;

    const int s0 = (blk * NSTEPS_TOTAL) / GEMM_BLOCKS;
    const int s1 = ((blk + 1) * NSTEPS_TOTAL) / GEMM_BLOCKS;

    // locate starting strip: cum(by) = by*(260-4*by) steps before strip by
    int by = 0;
    while (by < 31 && (by + 1) * (260 - 4 * (by + 1)) <= s0) ++by;
    int t = s0 - by * (260 - 4 * by);

    // ---- A fragments + row-label mask for current strip (64 rows x K=256 per wave)
    short8 a[4][8];
    unsigned rl;   // 16 bits: label of acc row (mt,quad,r) at bit mt*4+r
    {
        int rw0 = by * 256 + w * 64;
#pragma unroll
        for (int mt = 0; mt < 4; ++mt)
#pragma unroll
            for (int ki = 0; ki < 8; ++ki)
                a[mt][ki] = *(const short8*)(hA +
                    (size_t)(rw0 + mt * 16 + l15) * NDIM + ki * 32 + quad * 8);
        unsigned rb0 = lblbits[rw0 >> 5], rb1 = lblbits[(rw0 >> 5) + 1];
        rl = 0;
#pragma unroll
        for (int mt = 0; mt < 4; ++mt)
#pragma unroll
            for (int r = 0; r < 4; ++r) {
                unsigned rb = (mt < 2) ? rb0 : rb1;
                rl |= ((rb >> ((mt & 1) * 16 + quad * 4 + r)) & 1u) << (mt * 4 + r);
            }
    }

    float rowS[4][4];
#pragma unroll
    for (int mt = 0; mt < 4; ++mt)
#pragma unroll
        for (int r = 0; r < 4; ++r) rowS[mt][r] = 0.f;

    stage_b(hA, smem, 0, by * 256 + t * 32, w, lane);   // buf0 loads in flight

    for (int s = s0; s < s1; ++s) {
        const int buf = (s - s0) & 1;
        const int nst = 256 - 8 * by;
        const bool strip_end = (t == nst - 1);
        const int byn = strip_end ? by + 1 : by;
        const int tn  = strip_end ? 0 : t + 1;

        // ---- counted-vmcnt sync (T4): prior-step loads landed; this step's fly
        if (s + 1 < s1) {
            stage_b(hA, smem, buf ^ 1, byn * 256 + tn * 32, w, lane);
            asm volatile("s_waitcnt vmcnt(8)" ::: "memory");
        } else {
            asm volatile("s_waitcnt vmcnt(0)" ::: "memory");
        }
        __builtin_amdgcn_s_barrier();   // all waves' buf loads landed

        const int colbase = by * 256 + t * 32;
        const unsigned cb = lblbits[colbase >> 5];
        const unsigned diff0 = rl ^ (((cb >> l15) & 1u) ? 0xFFFFu : 0u);
        const unsigned diff1 = rl ^ (((cb >> (16 + l15)) & 1u) ? 0xFFFFu : 0u);

        f32x4 acc0[4], acc1[4];
#pragma unroll
        for (int mt = 0; mt < 4; ++mt) {
            acc0[mt] = (f32x4){0.f, 0.f, 0.f, 0.f};
            acc1[mt] = (f32x4){0.f, 0.f, 0.f, 0.f};
        }
        const unsigned short* Bb = (const unsigned short*)smem + buf * 8192;
#pragma unroll
        for (int ki = 0; ki < 8; ++ki) {
            int sc = (ki * 4 + quad) ^ (l15 & 7);       // (16+l15)&7 == l15&7
            short8 b0 = *(const short8*)(Bb + l15 * 256 + sc * 8);
            short8 b1 = *(const short8*)(Bb + (16 + l15) * 256 + sc * 8);
#pragma unroll
            for (int mt = 0; mt < 4; ++mt) {
                acc0[mt] = __builtin_amdgcn_mfma_f32_16x16x32_bf16(a[mt][ki], b0, acc0[mt], 0, 0, 0);
                acc1[mt] = __builtin_amdgcn_mfma_f32_16x16x32_bf16(a[mt][ki], b1, acc1[mt], 0, 0, 0);
            }
        }
        float colS0 = 0.f, colS1 = 0.f;
#pragma unroll
        for (int mt = 0; mt < 4; ++mt)
#pragma unroll
            for (int r = 0; r < 4; ++r) {
                float bias0 = ((diff0 >> (mt * 4 + r)) & 1u) ? 0.f : MASK_BIAS;
                float bias1 = ((diff1 >> (mt * 4 + r)) & 1u) ? 0.f : MASK_BIAS;
                float e0 = exp2f(fmaf(acc0[mt][r], SC_LOG2E, bias0));
                float e1 = exp2f(fmaf(acc1[mt][r], SC_LOG2E, bias1));
                rowS[mt][r] += e0 + e1;
                colS0 += e0;
                colS1 += e1;
            }
        if (t >= 8) {   // off-diagonal step: credit S_col (pair's other side)
            colS0 += __shfl_xor(colS0, 16, 64);
            colS0 += __shfl_xor(colS0, 32, 64);
            colS1 += __shfl_xor(colS1, 16, 64);
            colS1 += __shfl_xor(colS1, 32, 64);
            if (quad == 0) {
                atomicAdd(&neg[colbase + l15], colS0);
                atomicAdd(&neg[colbase + 16 + l15], colS1);
            }
        }
        if (strip_end || s == s1 - 1) {
            // flush rowS for current strip
#pragma unroll
            for (int o = 1; o < 16; o <<= 1)
#pragma unroll
                for (int mt = 0; mt < 4; ++mt)
#pragma unroll
                    for (int r = 0; r < 4; ++r)
                        rowS[mt][r] += __shfl_xor(rowS[mt][r], o, 64);
            if (l15 == 0) {
                int rw0 = by * 256 + w * 64;
#pragma unroll
                for (int mt = 0; mt < 4; ++mt)
#pragma unroll
                    for (int r = 0; r < 4; ++r)
                        atomicAdd(&neg[rw0 + mt * 16 + quad * 4 + r], rowS[mt][r]);
            }
            if (s + 1 < s1) {   // load A for next strip, reset accumulators
                int rw0n = byn * 256 + w * 64;
#pragma unroll
                for (int mt = 0; mt < 4; ++mt)
#pragma unroll
                    for (int ki = 0; ki < 8; ++ki)
                        a[mt][ki] = *(const short8*)(hA +
                            (size_t)(rw0n + mt * 16 + l15) * NDIM + ki * 32 + quad * 8);
                unsigned rb0 = lblbits[rw0n >> 5], rb1 = lblbits[(rw0n >> 5) + 1];
                rl = 0;
#pragma unroll
                for (int mt = 0; mt < 4; ++mt)
#pragma unroll
                    for (int r = 0; r < 4; ++r) {
                        unsigned rb = (mt < 2) ? rb0 : rb1;
                        rl |= ((rb >> ((mt & 1) * 16 + quad * 4 + r)) & 1u) << (mt * 4 + r);
                    }
#pragma unroll
                for (int mt = 0; mt < 4; ++mt)
#pragma unroll
                    for (int r = 0; r < 4; ++r) rowS[mt][r] = 0.f;
            }
        }
        by = byn; t = tn;
        __builtin_amdgcn_s_barrier();   // readers done; next stage may overwrite
    }
}

// ================= rowloss + ticketed finalize (last block writes out)
__global__ __launch_bounds__(256) void rowloss_kernel(const unsigned short* __restrict__ hA,
                                                      const int* __restrict__ labels,
                                                      const float* __restrict__ neg,
                                                      const float* __restrict__ selfsim,
                                                      const float* __restrict__ csum,
                                                      const float* __restrict__ cnt,
                                                      float* __restrict__ pbuf,
                                                      int* __restrict__ ticket,
                                                      float* __restrict__ out) {
    __shared__ float csumS[2][256];
    __shared__ float red[8];
    __shared__ int lastFlag;
    const int tid = threadIdx.x, blk = blockIdx.x;
    const int w = tid >> 6, lane = tid & 63;

    float t0 = 0.f, t1 = 0.f;
#pragma unroll
    for (int r = 0; r < 16; ++r) {
        t0 += csum[r * 512 + tid];
        t1 += csum[r * 512 + 256 + tid];
    }
    csumS[0][tid] = t0;
    csumS[1][tid] = t1;
    __syncthreads();
    float c0v = 0.f, c1v = 0.f;
#pragma unroll
    for (int r = 0; r < 16; ++r) { c0v += cnt[r * 2]; c1v += cnt[r * 2 + 1]; }

    const int row0 = blk * 32;
    float wsum = 0.f, wcnt = 0.f;
    for (int i = 0; i < 8; ++i) {
        int row = row0 + w * 8 + i;
        int l = labels[row] & 1;
        ushort4 hv = *(const ushort4*)(hA + (size_t)row * NDIM + lane * 4);
        const float* cv = &csumS[l][lane * 4];
        float dot = bf2f(hv.x) * cv[0] + bf2f(hv.y) * cv[1] +
                    bf2f(hv.z) * cv[2] + bf2f(hv.w) * cv[3];
#pragma unroll
        for (int o = 32; o >= 1; o >>= 1) dot += __shfl_xor(dot, o, 64);
        if (lane == 0) {
            float pc = (l ? c1v : c0v) - 1.0f;
            float S = neg[row];
            if (pc > 0.5f) {
                wcnt += 1.f;
                if (S > 0.f)
                    wsum += logf(S) - (dot - selfsim[row]) * INVT / pc;
            }
        }
    }
    if (lane == 0) { red[w] = wsum; red[4 + w] = wcnt; }
    __syncthreads();
    if (tid == 0) {
        atomicExch(&pbuf[blk],       red[0] + red[1] + red[2] + red[3]);
        atomicExch(&pbuf[256 + blk], red[4] + red[5] + red[6] + red[7]);
        __threadfence();
        int old = atomicAdd(ticket, 1);
        lastFlag = (old == 255) ? 1 : 0;
    }
    __syncthreads();
    if (lastFlag && tid < 64) {
        __threadfence();
        float v = 0.f, c = 0.f;
#pragma unroll
        for (int k = 0; k < 4; ++k) {
            v += atomicAdd(&pbuf[k * 64 + tid], 0.0f);        // device-scope reads
            c += atomicAdd(&pbuf[256 + k * 64 + tid], 0.0f);
        }
#pragma unroll
        for (int o = 32; o >= 1; o >>= 1) {
            v += __shfl_xor(v, o, 64);
            c += __shfl_xor(c, o, 64);
        }
        if (tid == 0) out[0] = (c > 0.f) ? v / c : 0.f;
    }
}

extern "C" void kernel_launch(void* const* d_in, const int* in_sizes, int n_in,
                              void* d_out, int out_size, void* d_ws, size_t ws_size,
                              hipStream_t stream) {
    const float* x = (const float*)d_in[0];
    const int* labels = (const int*)d_in[1];

    unsigned short* hA = (unsigned short*)d_ws;              // N*D bf16 = 4 MB
    float* wsf       = (float*)d_ws;
    float* selfsim   = wsf + (size_t)NROWS * NDIM / 2;       // 8192
    float* neg       = selfsim + NROWS;                      // 8192
    float* csum      = neg + NROWS;                          // 16*512 = 8192
    float* cnt       = csum + 16 * 512;                      // 32
    float* pbuf      = cnt + 32;                             // 512
    int*   ticket    = (int*)(pbuf + 512);                   // 1
    unsigned* lblbits = (unsigned*)(ticket + 1);             // 256

    hipMemsetAsync(csum, 0, (16 * 512 + 32) * sizeof(float), stream);   // csum + cnt
    prep_kernel<<<256, 256, 0, stream>>>(x, labels, hA, selfsim, neg, csum, cnt, ticket, lblbits);
    gemm_kernel<<<GEMM_BLOCKS, 256, 0, stream>>>(hA, lblbits, neg);
    rowloss_kernel<<<256, 256, 0, stream>>>(hA, labels, neg, selfsim, csum, cnt,
                                            pbuf, ticket, (float*)d_out);
}